// Round 4
// baseline (313.577 us; speedup 1.0000x reference)
//
#include <hip/hip_runtime.h>

// QLSTM: T=64, B=256, D=512, NQ=6.
// Closed form for _qlayer: with C_w = cos(x_w + theta_w):
//   z0 = C1*C2*C3*C4*C5, z1 = C0*C1, z2 = C0*C1*C2, z3 = C0..C3, z4 = C0..C4, z5 = C0..C5
//
// gemm_pre (structure C): k distributed across lanes, rows across waves.
//   - lane l covers k = {l, 64+l, ..., 448+l}; A reads are perfectly coalesced
//     global dwords (no A staging, no k-loop barriers).
//   - W staged once per block into LDS, layout [k][26] (stride 26: 2-way banks
//     = free, 8B aligned for b64). 12 ds_read_b64 amortized over 96 FMAs
//     (4 rows x 24 cols per lane, v_pk_fma via float2 ext-vectors).
//   - epilogue: 2 quad_perm DPP add stages (VALU pipe) -> 16 quad partials
//     -> LDS reduction OVERLAID on the W region (barrier first) -> 53 KB total.
// qlstm_scan: 4 threads/batch (one per gate); gate exchange via mov_dpp
//   quad_perm broadcast (VALU, ~2cyc) instead of ds_swizzle (LDS, ~60cyc).

typedef float v2f __attribute__((ext_vector_type(2)));

__device__ __forceinline__ float fast_rcp(float x) { return __builtin_amdgcn_rcpf(x); }

template <int CTRL>
__device__ __forceinline__ float dpp_add(float x) {
    int t = __builtin_amdgcn_mov_dpp(__float_as_int(x), CTRL, 0xF, 0xF, true);
    return x + __int_as_float(t);
}

template <int G>
__device__ __forceinline__ float quad_bcast(float v) {
    // quad_perm [G,G,G,G]: broadcast lane G of each aligned quad (VALU pipe)
    int i = __builtin_amdgcn_mov_dpp(__float_as_int(v), G * 0x55, 0xF, 0xF, true);
    return __int_as_float(i);
}

__global__ __launch_bounds__(512, 3) void gemm_pre(
    const float* __restrict__ X,
    const float* __restrict__ Wf, const float* __restrict__ bf,
    const float* __restrict__ Wi, const float* __restrict__ bi,
    const float* __restrict__ Wu, const float* __restrict__ bu,
    const float* __restrict__ Wo, const float* __restrict__ bo,
    const float* __restrict__ thf, const float* __restrict__ thi,
    const float* __restrict__ thu, const float* __restrict__ tho,
    float* __restrict__ pre)
{
    // W_lds[k*26 + g*6 + j] = Wg[k][j]; 512*26 = 13312 floats = 53 KB.
    // Epilogue overlays red[w][v][quad] = red[(w*96+v)*16+q] (12288 floats).
    __shared__ float W_lds[13312];

    const int tid  = threadIdx.x;
    const int w    = tid >> 6;          // wave 0..7
    const int lane = tid & 63;
    const int rowbase = blockIdx.x * 32;  // 8 waves * 4 rows

    // ---- stage W into LDS (once per block; iteration i == gate i) ----
    #pragma unroll
    for (int i = 0; i < 4; ++i) {
        const float* Wp = (i==0)?Wf:(i==1)?Wi:(i==2)?Wu:Wo;
        int k = tid;                    // 512 threads == 512 k rows
        const float2* s = (const float2*)(Wp + k*6);
        float2* d = (float2*)(W_lds + k*26 + i*6);
        d[0] = s[0]; d[1] = s[1]; d[2] = s[2];
    }
    __syncthreads();

    // ---- main loop: 8 chunks of 64 k ----
    v2f acc[4][12];
    #pragma unroll
    for (int r = 0; r < 4; ++r)
        #pragma unroll
        for (int p = 0; p < 12; ++p) acc[r][p] = (v2f){0.f, 0.f};

    const float* Xr0 = X + (rowbase + w*4)*512 + lane;

    #pragma unroll
    for (int kb = 0; kb < 512; kb += 64) {
        float a0 = Xr0[kb];
        float a1 = Xr0[kb + 512];
        float a2 = Xr0[kb + 1024];
        float a3 = Xr0[kb + 1536];
        const v2f* wrow = (const v2f*)(W_lds + (kb + lane)*26);
        #pragma unroll
        for (int p = 0; p < 12; ++p) {
            v2f wv = wrow[p];
            acc[0][p] = __builtin_elementwise_fma((v2f){a0,a0}, wv, acc[0][p]);
            acc[1][p] = __builtin_elementwise_fma((v2f){a1,a1}, wv, acc[1][p]);
            acc[2][p] = __builtin_elementwise_fma((v2f){a2,a2}, wv, acc[2][p]);
            acc[3][p] = __builtin_elementwise_fma((v2f){a3,a3}, wv, acc[3][p]);
        }
    }

    // ---- reduction: flat value v = r*24 + col, col = 2p+e (acc layout) ----
    float* af = (float*)acc;            // af[v], v in [0,96)
    #pragma unroll
    for (int v = 0; v < 96; ++v) {
        float x = af[v];
        x = dpp_add<0xB1>(x);           // quad_perm [1,0,3,2]: xor 1
        x = dpp_add<0x4E>(x);           // quad_perm [2,3,0,1]: xor 2
        af[v] = x;                      // all quad lanes hold quad sum
    }

    __syncthreads();                    // everyone done reading W_lds
    {
        const int q = lane >> 2;        // quad 0..15
        const int j = lane & 3;
        #pragma unroll
        for (int i = 0; i < 24; ++i) {
            int v = i*4 + j;
            // addr = w*1536 + i*64 + (j*16 + q): 64 consecutive dwords/inst
            W_lds[(w*96 + v)*16 + q] = af[v];
        }
    }
    __syncthreads();

    // ---- final: 768 outputs per block (8 waves * 4 rows * 24 cols) ----
    for (int o = tid; o < 768; o += 512) {
        int ww = o / 96, v = o - ww*96;
        int rr = v / 24, j = v - rr*24;
        const float4* rp = (const float4*)(W_lds + (ww*96 + v)*16);
        float4 r0 = rp[0], r1 = rp[1], r2 = rp[2], r3 = rp[3];
        float s = ((r0.x+r0.y)+(r0.z+r0.w)) + ((r1.x+r1.y)+(r1.z+r1.w))
                + ((r2.x+r2.y)+(r2.z+r2.w)) + ((r3.x+r3.y)+(r3.z+r3.w));
        int g = j / 6, jj = j - g*6;
        const float* bb = (g==0)?bf:(g==1)?bi:(g==2)?bu:bo;
        const float* tt = (g==0)?thf:(g==1)?thi:(g==2)?thu:tho;
        s += bb[jj] + tt[jj];
        int row = rowbase + ww*4 + rr;
        pre[row*24 + j] = s;
    }
}

__global__ __launch_bounds__(64, 1) void qlstm_scan(
    const float* __restrict__ pre,
    const float* __restrict__ Wf, const float* __restrict__ Wi,
    const float* __restrict__ Wu, const float* __restrict__ Wo,
    float* __restrict__ out)
{
    // 4 threads per batch element (one per gate), one aligned hw quad per batch.
    const int lane = threadIdx.x;
    const int bl   = lane >> 2;          // batch-local 0..15
    const int g    = lane & 3;           // 0=f 1=i 2=u 3=o
    const int b    = blockIdx.x * 16 + bl;

    // this gate's recurrent weights in registers (rows 512..517 of Wg)
    const float* Wg = (g==0)?Wf:(g==1)?Wi:(g==2)?Wu:Wo;
    float Wh[6][6];
    #pragma unroll
    for (int j = 0; j < 6; ++j)
        #pragma unroll
        for (int w = 0; w < 6; ++w)
            Wh[j][w] = Wg[(512 + j)*6 + w];

    // tanh(x) = 2*sigmoid(2x)-1 -> branchless per-gate constants
    const float k1 = (g==2) ? 2.f : 1.f;
    const float k2 = (g==2) ? 2.f : 1.f;
    const float k3 = (g==2) ? -1.f : 0.f;

    float h[6], c[6];
    #pragma unroll
    for (int w = 0; w < 6; ++w) { h[w] = 0.f; c[w] = 0.f; }

    // prefetch t=0
    const float* p0 = pre + b*24 + g*6;
    float2 x0 = *(const float2*)(p0);
    float2 x1 = *(const float2*)(p0 + 2);
    float2 x2 = *(const float2*)(p0 + 4);

    for (int t = 0; t < 64; ++t) {
        float xw[6] = {x0.x, x0.y, x1.x, x1.y, x2.x, x2.y};
        // prefetch next step (address independent of state)
        int tn = (t < 63) ? (t + 1) : 63;
        const float* pn = pre + (tn*256 + b)*24 + g*6;
        x0 = *(const float2*)(pn);
        x1 = *(const float2*)(pn + 2);
        x2 = *(const float2*)(pn + 4);

        float a[6];
        #pragma unroll
        for (int w = 0; w < 6; ++w) a[w] = xw[w];
        #pragma unroll
        for (int j = 0; j < 6; ++j)
            #pragma unroll
            for (int w = 0; w < 6; ++w)
                a[w] = fmaf(h[j], Wh[j][w], a[w]);

        float C[6];
        #pragma unroll
        for (int w = 0; w < 6; ++w) C[w] = __cosf(a[w]);

        // tree-structured products (depth 3)
        float p01 = C[0]*C[1], p23 = C[2]*C[3], p45 = C[4]*C[5];
        float z[6];
        z[1] = p01;
        z[2] = p01*C[2];
        z[3] = p01*p23;
        z[4] = z[3]*C[4];
        z[5] = z[3]*p45;
        z[0] = C[1]*(p23*p45);

        float act[6];
        #pragma unroll
        for (int w = 0; w < 6; ++w) {
            float e = __expf(-k1 * z[w]);
            act[w] = fmaf(k2, fast_rcp(1.f + e), k3);
        }

        // quad-broadcast exchange via DPP: all four gates' act[6] to every lane
        float F[6], I[6], U[6], O[6];
        #pragma unroll
        for (int w = 0; w < 6; ++w) {
            F[w] = quad_bcast<0>(act[w]);
            I[w] = quad_bcast<1>(act[w]);
            U[w] = quad_bcast<2>(act[w]);
            O[w] = quad_bcast<3>(act[w]);
        }

        #pragma unroll
        for (int w = 0; w < 6; ++w) {
            c[w] = fmaf(F[w], c[w], I[w]*U[w]);
            float e  = __expf(-2.f * c[w]);
            float tc = fmaf(2.f, fast_rcp(1.f + e), -1.f);
            h[w] = O[w]*tc;
        }

        if (g < 3) {
            float2 v;
            v.x = (g==0) ? h[0] : (g==1) ? h[2] : h[4];
            v.y = (g==0) ? h[1] : (g==1) ? h[3] : h[5];
            *(float2*)(out + (t*256 + b)*6 + g*2) = v;
        }
    }

    if (g < 3) {
        float2 v;
        v.x = (g==0) ? h[0] : (g==1) ? h[2] : h[4];
        v.y = (g==0) ? h[1] : (g==1) ? h[3] : h[5];
        *(float2*)(out + 64*256*6 + b*6 + g*2) = v;
        float2 u;
        u.x = (g==0) ? c[0] : (g==1) ? c[2] : c[4];
        u.y = (g==0) ? c[1] : (g==1) ? c[3] : c[5];
        *(float2*)(out + 64*256*6 + 256*6 + b*6 + g*2) = u;
    }
}

extern "C" void kernel_launch(void* const* d_in, const int* in_sizes, int n_in,
                              void* d_out, int out_size, void* d_ws, size_t ws_size,
                              hipStream_t stream) {
    const float* X   = (const float*)d_in[0];
    const float* Wf  = (const float*)d_in[1];
    const float* bf_ = (const float*)d_in[2];
    const float* Wi  = (const float*)d_in[3];
    const float* bi_ = (const float*)d_in[4];
    const float* Wu  = (const float*)d_in[5];
    const float* bu_ = (const float*)d_in[6];
    const float* Wo  = (const float*)d_in[7];
    const float* bo_ = (const float*)d_in[8];
    const float* thf = (const float*)d_in[9];
    const float* thi = (const float*)d_in[10];
    const float* thu = (const float*)d_in[11];
    const float* tho = (const float*)d_in[12];

    float* pre = (float*)d_ws;           // 16384*24 floats = 1.57 MB
    float* out = (float*)d_out;

    gemm_pre<<<512, 512, 0, stream>>>(X, Wf, bf_, Wi, bi_, Wu, bu_, Wo, bo_,
                                      thf, thi, thu, tho, pre);
    qlstm_scan<<<16, 64, 0, stream>>>(pre, Wf, Wi, Wu, Wo, out);
}

// Round 5
// 140.730 us; speedup vs baseline: 2.2282x; 2.2282x over previous
//
#include <hip/hip_runtime.h>

// QLSTM: T=64, B=256, D=512, NQ=6.
// Closed form for _qlayer: with C_w = cos(x_w + theta_w):
//   z0 = C1*C2*C3*C4*C5, z1 = C0*C1, z2 = C0*C1*C2, z3 = C0..C3, z4 = C0..C4, z5 = C0..C6
//
// gemm_pre: k distributed across lanes, rows across waves.
//   - lane l covers k = {l, 64+l, ..., 448+l}; A reads are perfectly coalesced
//     global dwords (no A staging, no k-loop barriers).
//   - W staged once per block into LDS, layout [k][26] (stride 26, 8B aligned).
//     12 ds_read_b64 amortized over 96 FMAs per chunk (4 rows x 24 cols/lane).
//   - reduction: quad DPP adds with STATIC register indexing only; the
//     lane-dependent selection (v = i*4 + (lane&3)) is done with cndmask
//     selects over statically-indexed candidates -- NO dynamic indexing into
//     register arrays (R4's scratch-spill bug: 845 MB scratch traffic).
//   - 16 quad-partials -> LDS (overlaid on W region after barrier) -> final sum.
// qlstm_scan: 4 threads/batch (one per gate); gate exchange via mov_dpp
//   quad_perm broadcast (VALU pipe, no LDS, no barriers).

typedef float v2f __attribute__((ext_vector_type(2)));

__device__ __forceinline__ float fast_rcp(float x) { return __builtin_amdgcn_rcpf(x); }

template <int CTRL>
__device__ __forceinline__ float dpp_add(float x) {
    int t = __builtin_amdgcn_mov_dpp(__float_as_int(x), CTRL, 0xF, 0xF, true);
    return x + __int_as_float(t);
}

template <int G>
__device__ __forceinline__ float quad_bcast(float v) {
    // quad_perm [G,G,G,G]: broadcast lane G of each aligned quad (VALU pipe)
    int i = __builtin_amdgcn_mov_dpp(__float_as_int(v), G * 0x55, 0xF, 0xF, true);
    return __int_as_float(i);
}

__global__ __launch_bounds__(512, 2) void gemm_pre(
    const float* __restrict__ X,
    const float* __restrict__ Wf, const float* __restrict__ bf,
    const float* __restrict__ Wi, const float* __restrict__ bi,
    const float* __restrict__ Wu, const float* __restrict__ bu,
    const float* __restrict__ Wo, const float* __restrict__ bo,
    const float* __restrict__ thf, const float* __restrict__ thi,
    const float* __restrict__ thu, const float* __restrict__ tho,
    float* __restrict__ pre)
{
    // W_lds[k*26 + g*6 + j] = Wg[k][j]; 512*26 = 13312 floats = 53 KB.
    // Epilogue overlays red[(w*96+v)*16+q] (12288 floats).
    __shared__ float W_lds[13312];

    const int tid  = threadIdx.x;
    const int w    = tid >> 6;          // wave 0..7
    const int lane = tid & 63;
    const int rowbase = blockIdx.x * 32;  // 8 waves * 4 rows

    // ---- stage W into LDS (once per block; iteration i == gate i) ----
    #pragma unroll
    for (int i = 0; i < 4; ++i) {
        const float* Wp = (i==0)?Wf:(i==1)?Wi:(i==2)?Wu:Wo;
        int k = tid;                    // 512 threads == 512 k rows
        const float2* s = (const float2*)(Wp + k*6);
        float2* d = (float2*)(W_lds + k*26 + i*6);
        d[0] = s[0]; d[1] = s[1]; d[2] = s[2];
    }
    __syncthreads();

    // ---- main loop: 8 chunks of 64 k ----
    v2f acc[4][12];
    #pragma unroll
    for (int r = 0; r < 4; ++r)
        #pragma unroll
        for (int p = 0; p < 12; ++p) acc[r][p] = (v2f){0.f, 0.f};

    const float* Xr0 = X + (rowbase + w*4)*512 + lane;

    #pragma unroll
    for (int kb = 0; kb < 512; kb += 64) {
        float a0 = Xr0[kb];
        float a1 = Xr0[kb + 512];
        float a2 = Xr0[kb + 1024];
        float a3 = Xr0[kb + 1536];
        const v2f* wrow = (const v2f*)(W_lds + (kb + lane)*26);
        #pragma unroll
        for (int p = 0; p < 12; ++p) {
            v2f wv = wrow[p];
            acc[0][p] = __builtin_elementwise_fma((v2f){a0,a0}, wv, acc[0][p]);
            acc[1][p] = __builtin_elementwise_fma((v2f){a1,a1}, wv, acc[1][p]);
            acc[2][p] = __builtin_elementwise_fma((v2f){a2,a2}, wv, acc[2][p]);
            acc[3][p] = __builtin_elementwise_fma((v2f){a3,a3}, wv, acc[3][p]);
        }
    }

    // ---- quad reduction: static indexing only ----
    #pragma unroll
    for (int r = 0; r < 4; ++r)
        #pragma unroll
        for (int p = 0; p < 12; ++p) {
            float x = acc[r][p].x;
            x = dpp_add<0xB1>(x);       // quad_perm [1,0,3,2]
            x = dpp_add<0x4E>(x);       // quad_perm [2,3,0,1]
            acc[r][p].x = x;
            float y = acc[r][p].y;
            y = dpp_add<0xB1>(y);
            y = dpp_add<0x4E>(y);
            acc[r][p].y = y;
        }

    // flat value v = r*24 + col, col = 2p + e  ->  acc[v/24][(v%24)/2].{x|y}
    #define ACCV(v) ((((v) & 1) == 0) ? acc[(v)/24][((v)%24)/2].x \
                                      : acc[(v)/24][((v)%24)/2].y)
    const int j = lane & 3;             // which of the 4 values this lane stores
    const int q = lane >> 2;            // quad index 0..15
    const bool j1 = (j & 1) != 0, j2 = (j & 2) != 0;
    float sel[24];
    #pragma unroll
    for (int i = 0; i < 24; ++i) {
        float c0 = ACCV(i*4 + 0), c1 = ACCV(i*4 + 1);
        float c2 = ACCV(i*4 + 2), c3 = ACCV(i*4 + 3);
        float lo = j1 ? c1 : c0;
        float hi = j1 ? c3 : c2;
        sel[i] = j2 ? hi : lo;
    }
    #undef ACCV

    __syncthreads();                    // everyone done reading W_lds
    #pragma unroll
    for (int i = 0; i < 24; ++i) {
        // addr = w*1536 + i*64 + (j*16 + q): 64 consecutive dwords per wave
        W_lds[(w*96 + i*4 + j)*16 + q] = sel[i];
    }
    __syncthreads();

    // ---- final: 768 outputs per block (8 waves * 4 rows * 24 cols) ----
    for (int o = tid; o < 768; o += 512) {
        int ww = o / 96, v = o - ww*96;
        int rr = v / 24, jj24 = v - rr*24;
        const float4* rp = (const float4*)(W_lds + (ww*96 + v)*16);
        float4 r0 = rp[0], r1 = rp[1], r2 = rp[2], r3 = rp[3];
        float s = ((r0.x+r0.y)+(r0.z+r0.w)) + ((r1.x+r1.y)+(r1.z+r1.w))
                + ((r2.x+r2.y)+(r2.z+r2.w)) + ((r3.x+r3.y)+(r3.z+r3.w));
        int g = jj24 / 6, jg = jj24 - g*6;
        const float* bb = (g==0)?bf:(g==1)?bi:(g==2)?bu:bo;
        const float* tt = (g==0)?thf:(g==1)?thi:(g==2)?thu:tho;
        s += bb[jg] + tt[jg];
        int row = rowbase + ww*4 + rr;
        pre[row*24 + jj24] = s;
    }
}

__global__ __launch_bounds__(64, 1) void qlstm_scan(
    const float* __restrict__ pre,
    const float* __restrict__ Wf, const float* __restrict__ Wi,
    const float* __restrict__ Wu, const float* __restrict__ Wo,
    float* __restrict__ out)
{
    // 4 threads per batch element (one per gate), one aligned hw quad per batch.
    const int lane = threadIdx.x;
    const int bl   = lane >> 2;          // batch-local 0..15
    const int g    = lane & 3;           // 0=f 1=i 2=u 3=o
    const int b    = blockIdx.x * 16 + bl;

    // this gate's recurrent weights in registers (rows 512..517 of Wg)
    const float* Wg = (g==0)?Wf:(g==1)?Wi:(g==2)?Wu:Wo;
    float Wh[6][6];
    #pragma unroll
    for (int j = 0; j < 6; ++j)
        #pragma unroll
        for (int w = 0; w < 6; ++w)
            Wh[j][w] = Wg[(512 + j)*6 + w];

    // tanh(x) = 2*sigmoid(2x)-1 -> branchless per-gate constants
    const float k1 = (g==2) ? 2.f : 1.f;
    const float k2 = (g==2) ? 2.f : 1.f;
    const float k3 = (g==2) ? -1.f : 0.f;

    float h[6], c[6];
    #pragma unroll
    for (int w = 0; w < 6; ++w) { h[w] = 0.f; c[w] = 0.f; }

    // prefetch t=0
    const float* p0 = pre + b*24 + g*6;
    float2 x0 = *(const float2*)(p0);
    float2 x1 = *(const float2*)(p0 + 2);
    float2 x2 = *(const float2*)(p0 + 4);

    for (int t = 0; t < 64; ++t) {
        float xw[6] = {x0.x, x0.y, x1.x, x1.y, x2.x, x2.y};
        // prefetch next step (address independent of state)
        int tn = (t < 63) ? (t + 1) : 63;
        const float* pn = pre + (tn*256 + b)*24 + g*6;
        x0 = *(const float2*)(pn);
        x1 = *(const float2*)(pn + 2);
        x2 = *(const float2*)(pn + 4);

        float a[6];
        #pragma unroll
        for (int w = 0; w < 6; ++w) a[w] = xw[w];
        #pragma unroll
        for (int j = 0; j < 6; ++j)
            #pragma unroll
            for (int w = 0; w < 6; ++w)
                a[w] = fmaf(h[j], Wh[j][w], a[w]);

        float C[6];
        #pragma unroll
        for (int w = 0; w < 6; ++w) C[w] = __cosf(a[w]);

        // tree-structured products (depth 3)
        float p01 = C[0]*C[1], p23 = C[2]*C[3], p45 = C[4]*C[5];
        float z[6];
        z[1] = p01;
        z[2] = p01*C[2];
        z[3] = p01*p23;
        z[4] = z[3]*C[4];
        z[5] = z[3]*p45;
        z[0] = C[1]*(p23*p45);

        float act[6];
        #pragma unroll
        for (int w = 0; w < 6; ++w) {
            float e = __expf(-k1 * z[w]);
            act[w] = fmaf(k2, fast_rcp(1.f + e), k3);
        }

        // quad-broadcast exchange via DPP: all four gates' act[6] to every lane
        float F[6], I[6], U[6], O[6];
        #pragma unroll
        for (int w = 0; w < 6; ++w) {
            F[w] = quad_bcast<0>(act[w]);
            I[w] = quad_bcast<1>(act[w]);
            U[w] = quad_bcast<2>(act[w]);
            O[w] = quad_bcast<3>(act[w]);
        }

        #pragma unroll
        for (int w = 0; w < 6; ++w) {
            c[w] = fmaf(F[w], c[w], I[w]*U[w]);
            float e  = __expf(-2.f * c[w]);
            float tc = fmaf(2.f, fast_rcp(1.f + e), -1.f);
            h[w] = O[w]*tc;
        }

        if (g < 3) {
            float2 v;
            v.x = (g==0) ? h[0] : (g==1) ? h[2] : h[4];
            v.y = (g==0) ? h[1] : (g==1) ? h[3] : h[5];
            *(float2*)(out + (t*256 + b)*6 + g*2) = v;
        }
    }

    if (g < 3) {
        float2 v;
        v.x = (g==0) ? h[0] : (g==1) ? h[2] : h[4];
        v.y = (g==0) ? h[1] : (g==1) ? h[3] : h[5];
        *(float2*)(out + 64*256*6 + b*6 + g*2) = v;
        float2 u;
        u.x = (g==0) ? c[0] : (g==1) ? c[2] : c[4];
        u.y = (g==0) ? c[1] : (g==1) ? c[3] : c[5];
        *(float2*)(out + 64*256*6 + 256*6 + b*6 + g*2) = u;
    }
}

extern "C" void kernel_launch(void* const* d_in, const int* in_sizes, int n_in,
                              void* d_out, int out_size, void* d_ws, size_t ws_size,
                              hipStream_t stream) {
    const float* X   = (const float*)d_in[0];
    const float* Wf  = (const float*)d_in[1];
    const float* bf_ = (const float*)d_in[2];
    const float* Wi  = (const float*)d_in[3];
    const float* bi_ = (const float*)d_in[4];
    const float* Wu  = (const float*)d_in[5];
    const float* bu_ = (const float*)d_in[6];
    const float* Wo  = (const float*)d_in[7];
    const float* bo_ = (const float*)d_in[8];
    const float* thf = (const float*)d_in[9];
    const float* thi = (const float*)d_in[10];
    const float* thu = (const float*)d_in[11];
    const float* tho = (const float*)d_in[12];

    float* pre = (float*)d_ws;           // 16384*24 floats = 1.57 MB
    float* out = (float*)d_out;

    gemm_pre<<<512, 512, 0, stream>>>(X, Wf, bf_, Wi, bi_, Wu, bu_, Wo, bo_,
                                      thf, thi, thu, tho, pre);
    qlstm_scan<<<16, 64, 0, stream>>>(pre, Wf, Wi, Wu, Wo, out);
}